// Round 1
// 741.238 us; speedup vs baseline: 1.1841x; 1.1841x over previous
//
#include <hip/hip_runtime.h>
#include <hip/hip_bf16.h>

#define N_NODES 100000
#define N_EDGES 1600000
#define IN_DIM 128
#define OUT_DIM 64
#define EDGE_DIM 32
#define NH 4
#define HD 16
#define NEG_SLOPE 0.2f

#define W_SRC_ELEMS (OUT_DIM * IN_DIM)   // 8192
#define W_EDGE_ELEMS (OUT_DIM * EDGE_DIM) // 2048
#define W_TOTAL (2 * W_SRC_ELEMS + W_EDGE_ELEMS) // 18432

typedef __attribute__((ext_vector_type(8))) short short8;
typedef __attribute__((ext_vector_type(4))) float floatx4;

// Split an fp32 octet into bf16 hi/lo fragments: x = hi + lo + O(eps^2 * x).
// hi*hi + hi*lo + lo*hi MFMAs give ~1e-5 relative dot-product error.
__device__ __forceinline__ void cvt_hilo(const float* __restrict__ p, short8& hi, short8& lo)
{
    float4 x0 = *(const float4*)p;
    float4 x1 = *(const float4*)(p + 4);
    float v[8] = {x0.x, x0.y, x0.z, x0.w, x1.x, x1.y, x1.z, x1.w};
#pragma unroll
    for (int j = 0; j < 8; ++j) {
        union { __hip_bfloat16 b; short s; } h, l;
        h.b = __float2bfloat16(v[j]);
        l.b = __float2bfloat16(v[j] - __bfloat162float(h.b));
        hi[j] = h.s;
        lo[j] = l.s;
    }
}

// ---------------------------------------------------------------------------
// Kernel W: precompute hi/lo bf16 split of W_src|W_dst|W_edge (one pass).
// ---------------------------------------------------------------------------
__global__ __launch_bounds__(256) void wsplit_kernel(
    const float* __restrict__ W_src,
    const float* __restrict__ W_dst,
    const float* __restrict__ W_edge,
    short* __restrict__ w_hi,
    short* __restrict__ w_lo)
{
    int g = blockIdx.x * 256 + threadIdx.x;
    if (g >= W_TOTAL) return;
    float v;
    if (g < W_SRC_ELEMS)            v = W_src[g];
    else if (g < 2 * W_SRC_ELEMS)   v = W_dst[g - W_SRC_ELEMS];
    else                            v = W_edge[g - 2 * W_SRC_ELEMS];
    union { __hip_bfloat16 b; short s; } h, l;
    h.b = __float2bfloat16(v);
    l.b = __float2bfloat16(v - __bfloat162float(h.b));
    w_hi[g] = h.s;
    w_lo[g] = l.s;
}

// ---------------------------------------------------------------------------
// Kernel A: feat_src = node_feat @ W_src^T, feat_dst = node_feat @ W_dst^T
// One wave per 16-node tile; 8 o-tiles (4 src + 4 dst); split-bf16 MFMA.
// ---------------------------------------------------------------------------
__global__ __launch_bounds__(64) void node_proj_kernel(
    const float* __restrict__ node_feat,
    const short* __restrict__ w_hi,
    const short* __restrict__ w_lo,
    float* __restrict__ feat_src,
    float* __restrict__ feat_dst)
{
    const int lane = threadIdx.x;
    const int col  = lane & 15;
    const int quad = lane >> 4;
    const int m0   = blockIdx.x * 16;

    floatx4 acc[8];
#pragma unroll
    for (int t = 0; t < 8; ++t) acc[t] = (floatx4){0.f, 0.f, 0.f, 0.f};

#pragma unroll
    for (int kc = 0; kc < 4; ++kc) {
        short8 ahi, alo;
        cvt_hilo(node_feat + (size_t)(m0 + col) * IN_DIM + kc * 32 + quad * 8, ahi, alo);
#pragma unroll
        for (int t = 0; t < 8; ++t) {
            int o = (t < 4 ? 0 : OUT_DIM) + (t & 3) * 16 + col;
            size_t off = (size_t)o * IN_DIM + kc * 32 + quad * 8;
            short8 bhi = *(const short8*)(w_hi + off);
            short8 blo = *(const short8*)(w_lo + off);
            acc[t] = __builtin_amdgcn_mfma_f32_16x16x32_bf16(ahi, bhi, acc[t], 0, 0, 0);
            acc[t] = __builtin_amdgcn_mfma_f32_16x16x32_bf16(ahi, blo, acc[t], 0, 0, 0);
            acc[t] = __builtin_amdgcn_mfma_f32_16x16x32_bf16(alo, bhi, acc[t], 0, 0, 0);
        }
    }

#pragma unroll
    for (int t = 0; t < 8; ++t) {
        float* out = (t < 4) ? feat_src : feat_dst;
        int ob = (t & 3) * 16;
#pragma unroll
        for (int r = 0; r < 4; ++r) {
            int node = m0 + quad * 4 + r;
            out[(size_t)node * OUT_DIM + ob + col] = acc[t][r];
        }
    }
}

// ---------------------------------------------------------------------------
// Kernel B: edge logits + exp. ex written to the alpha output slot.
// Only ONE atomic per edge remains (degree histogram); seg_sum is now
// computed downstream in the aggregate kernel (bucket order, no atomics).
// ---------------------------------------------------------------------------
__global__ __launch_bounds__(256) void edge_logits_kernel(
    const float* __restrict__ edge_feat,
    const short* __restrict__ we_hi,   // W_edge hi, [64][32]
    const short* __restrict__ we_lo,
    const float* __restrict__ attn,
    const int* __restrict__ src,
    const int* __restrict__ dst,
    const float* __restrict__ feat_src,
    const float* __restrict__ feat_dst,
    float* __restrict__ ex_out,
    int* __restrict__ deg)
{
    const int lane = threadIdx.x & 63;
    const int wave = threadIdx.x >> 6;
    const int col  = lane & 15;
    const int quad = lane >> 4;
    const size_t ebase = ((size_t)blockIdx.x * 4 + wave) * 16;

    short8 ahi, alo;
    cvt_hilo(edge_feat + (ebase + col) * EDGE_DIM + quad * 8, ahi, alo);

    floatx4 acc[4];
#pragma unroll
    for (int t = 0; t < 4; ++t) {
        size_t off = (size_t)(t * 16 + col) * EDGE_DIM + quad * 8;
        short8 bhi = *(const short8*)(we_hi + off);
        short8 blo = *(const short8*)(we_lo + off);
        floatx4 c = (floatx4){0.f, 0.f, 0.f, 0.f};
        c = __builtin_amdgcn_mfma_f32_16x16x32_bf16(ahi, bhi, c, 0, 0, 0);
        c = __builtin_amdgcn_mfma_f32_16x16x32_bf16(ahi, blo, c, 0, 0, 0);
        c = __builtin_amdgcn_mfma_f32_16x16x32_bf16(alo, bhi, c, 0, 0, 0);
        acc[t] = c;
    }

    float att[4];
#pragma unroll
    for (int t = 0; t < 4; ++t) att[t] = attn[t * 16 + col];

    int s[4], d[4];
#pragma unroll
    for (int r = 0; r < 4; ++r) {
        s[r] = src[ebase + quad * 4 + r];
        d[r] = dst[ebase + quad * 4 + r];
    }

    float sums[16];
#pragma unroll
    for (int r = 0; r < 4; ++r) {
#pragma unroll
        for (int t = 0; t < 4; ++t) {
            float v = acc[t][r]
                    + feat_src[(size_t)s[r] * OUT_DIM + t * 16 + col]
                    + feat_dst[(size_t)d[r] * OUT_DIM + t * 16 + col];
            v = (v > 0.f) ? v : NEG_SLOPE * v;
            float p = v * att[t];
            p += __shfl_xor(p, 1);
            p += __shfl_xor(p, 2);
            p += __shfl_xor(p, 4);
            p += __shfl_xor(p, 8);
            sums[r * 4 + t] = p;
        }
    }

    // lane j in quad picks (r = j>>2, h = j&3); ex index collapses to ebase*4+lane
    const int j = col;
    const int rsel = j >> 2;
    float logit = sums[0];
#pragma unroll
    for (int i = 1; i < 16; ++i) logit = (j == i) ? sums[i] : logit;
    float ev = __expf(logit);
    ex_out[ebase * NH + lane] = ev;

    int dd = d[0];
#pragma unroll
    for (int r = 1; r < 4; ++r) dd = (rsel == r) ? d[r] : dd;
    if ((j & 3) == 0) atomicAdd(&deg[dd], 1);   // one lane per edge
}

// ---------------------------------------------------------------------------
// Hierarchical scan of deg[N] -> row_ptr[N+1] (exclusive), cursor[N].
// ---------------------------------------------------------------------------
#define SCAN_BLOCKS 98

__global__ __launch_bounds__(256) void scan_phase1(
    const int* __restrict__ deg, int* __restrict__ partial)
{
    __shared__ int red[256];
    const int tid = threadIdx.x;
    const int base = blockIdx.x * 1024 + tid * 4;
    int s = 0;
#pragma unroll
    for (int i = 0; i < 4; ++i) {
        int idx = base + i;
        if (idx < N_NODES) s += deg[idx];
    }
    red[tid] = s;
    __syncthreads();
    for (int off = 128; off > 0; off >>= 1) {
        if (tid < off) red[tid] += red[tid + off];
        __syncthreads();
    }
    if (tid == 0) partial[blockIdx.x] = red[0];
}

__global__ __launch_bounds__(128) void scan_phase2(
    const int* __restrict__ partial, int* __restrict__ block_off, int* __restrict__ row_ptr)
{
    __shared__ int buf[128];
    const int tid = threadIdx.x;
    buf[tid] = (tid < SCAN_BLOCKS) ? partial[tid] : 0;
    __syncthreads();
    for (int off = 1; off < 128; off <<= 1) {
        int v = buf[tid];
        int add = (tid >= off) ? buf[tid - off] : 0;
        __syncthreads();
        buf[tid] = v + add;
        __syncthreads();
    }
    if (tid < SCAN_BLOCKS) block_off[tid] = (tid > 0) ? buf[tid - 1] : 0;
    if (tid == 0) row_ptr[N_NODES] = N_EDGES;
}

__global__ __launch_bounds__(256) void scan_phase3(
    const int* __restrict__ deg, const int* __restrict__ block_off,
    int* __restrict__ row_ptr, int* __restrict__ cursor)
{
    __shared__ int tsum[256];
    const int tid = threadIdx.x;
    const int base = blockIdx.x * 1024 + tid * 4;
    int d[4];
    int s = 0;
#pragma unroll
    for (int i = 0; i < 4; ++i) {
        int idx = base + i;
        d[i] = (idx < N_NODES) ? deg[idx] : 0;
        s += d[i];
    }
    tsum[tid] = s;
    __syncthreads();
    for (int off = 1; off < 256; off <<= 1) {
        int v = tsum[tid];
        int add = (tid >= off) ? tsum[tid - off] : 0;
        __syncthreads();
        tsum[tid] = v + add;
        __syncthreads();
    }
    int prefix = block_off[blockIdx.x] + ((tid > 0) ? tsum[tid - 1] : 0);
#pragma unroll
    for (int i = 0; i < 4; ++i) {
        int idx = base + i;
        if (idx < N_NODES) {
            row_ptr[idx] = prefix;
            cursor[idx]  = prefix;
            prefix += d[i];
        }
    }
}

// ---------------------------------------------------------------------------
// Kernel F: bucket-fill in CONSUMPTION ORDER.
// Instead of just the edge index, materialize everything aggregate needs:
//   esrc[pos] = src[e]          (kills the eidx->src dependent gather)
//   exb [pos] = ex[e] (float4)  (kills the random 16B alpha gather; aggregate
//                                reads exb contiguously per bucket)
// exb reuses feat_dst's workspace slot (dead after edge_logits; same size).
// ---------------------------------------------------------------------------
__global__ __launch_bounds__(256) void bucket_fill_kernel(
    const int* __restrict__ dst,
    const int* __restrict__ src,
    const float* __restrict__ ex,      // [E][4], original edge order
    int* __restrict__ cursor,
    int* __restrict__ esrc,            // [E]
    float* __restrict__ exb)           // [E][4], bucket order
{
    int e = blockIdx.x * 256 + threadIdx.x;
    int pos = atomicAdd(&cursor[dst[e]], 1);
    esrc[pos] = src[e];
    float4 v = ((const float4*)ex)[e];
    ((float4*)exb)[pos] = v;
}

// ---------------------------------------------------------------------------
// Kernel G: gather-side aggregation. One wave per node; lane = h*16+hd.
// Reads esrc/exb CONTIGUOUSLY (bucket order); only feat_src is a gather.
// Computes seg_sum[node] as a byproduct (Sum of ex over the bucket) and
// normalizes in-register: out = (Sum ex*feat) / (Sum ex) + bias.
// ---------------------------------------------------------------------------
__global__ __launch_bounds__(256) void aggregate_kernel(
    const int* __restrict__ row_ptr,
    const int* __restrict__ esrc,
    const float* __restrict__ exb,
    const float* __restrict__ feat_src,
    const float* __restrict__ bias,
    float* __restrict__ seg_sum,
    float* __restrict__ out)
{
    const int node = blockIdx.x * 4 + (threadIdx.x >> 6);
    if (node >= N_NODES) return;
    const int lane = threadIdx.x & 63;
    const int h = lane >> 4;

    const int start = row_ptr[node];
    const int end   = row_ptr[node + 1];

    float acc = 0.f;
    float ssum = 0.f;
    int   s_cur = 0;
    float e_cur = 0.f;
    if (start < end) {
        s_cur = esrc[start];
        e_cur = exb[(size_t)start * NH + h];
    }
    for (int j = start; j < end; ++j) {
        int   s  = s_cur;
        float ev = e_cur;
        if (j + 1 < end) {
            s_cur = esrc[j + 1];
            e_cur = exb[(size_t)(j + 1) * NH + h];
        }
        acc  = fmaf(feat_src[(size_t)s * OUT_DIM + lane], ev, acc);
        ssum += ev;
    }

    // ssum is bitwise-identical across the 16 lanes of a head group
    if ((lane & 15) == 0) seg_sum[(size_t)node * NH + h] = ssum;
    float inv = (ssum > 0.f) ? 1.f / ssum : 0.f;
    out[(size_t)node * OUT_DIM + lane] = fmaf(acc, inv, bias[lane]);
}

// ---------------------------------------------------------------------------
// Kernel C: alpha = ex / seg_sum[dst]  (in place; runs AFTER aggregate now)
// ---------------------------------------------------------------------------
__global__ __launch_bounds__(256) void normalize_kernel(
    const float* __restrict__ seg_sum,
    const int* __restrict__ dst,
    float* __restrict__ alpha)
{
    int g = blockIdx.x * 256 + threadIdx.x;   // g < E*NH
    int e = g >> 2;
    int h = g & 3;
    alpha[g] = alpha[g] / seg_sum[(size_t)dst[e] * NH + h];
}

// ---------------------------------------------------------------------------
extern "C" void kernel_launch(void* const* d_in, const int* in_sizes, int n_in,
                              void* d_out, int out_size, void* d_ws, size_t ws_size,
                              hipStream_t stream)
{
    const float* node_feat = (const float*)d_in[0];
    const float* edge_feat = (const float*)d_in[1];
    const float* W_src     = (const float*)d_in[2];
    const float* W_dst     = (const float*)d_in[3];
    const float* W_edge    = (const float*)d_in[4];
    const float* attn      = (const float*)d_in[5];
    const float* bias      = (const float*)d_in[6];
    const int* src = (const int*)d_in[7];
    const int* dst = (const int*)d_in[8];

    // workspace layout (same footprint as before; exb aliases feat_dst)
    float* ws       = (float*)d_ws;
    float* feat_src = ws;                                        // N*64 floats
    float* feat_dst = feat_src + (size_t)N_NODES * OUT_DIM;      // N*64 floats (== E*NH!)
    float* exb      = feat_dst;                                  // reuse after edge_logits
    float* seg_sum  = feat_dst + (size_t)N_NODES * OUT_DIM;      // N*4 floats
    int*   deg      = (int*)(seg_sum + (size_t)N_NODES * NH);    // N ints
    int*   row_ptr  = deg + N_NODES;                             // N+1
    int*   cursor   = row_ptr + N_NODES + 1;                     // N
    int*   esrc     = cursor + N_NODES;                          // E ints (was eidx)
    int*   partial  = esrc + N_EDGES;                            // 98
    int*   boff     = partial + 128;                             // 98
    short* w_hi     = (short*)(boff + 128);                      // 18432 shorts
    short* w_lo     = w_hi + W_TOTAL;

    float* rst_out   = (float*)d_out;
    float* alpha_out = rst_out + (size_t)N_NODES * OUT_DIM;   // holds ex, then alpha

    hipMemsetAsync(deg, 0, (size_t)N_NODES * sizeof(int), stream);

    wsplit_kernel<<<(W_TOTAL + 255) / 256, 256, 0, stream>>>(W_src, W_dst, W_edge, w_hi, w_lo);
    node_proj_kernel<<<N_NODES / 16, 64, 0, stream>>>(node_feat, w_hi, w_lo, feat_src, feat_dst);
    edge_logits_kernel<<<N_EDGES / 64, 256, 0, stream>>>(edge_feat,
                                                         w_hi + 2 * W_SRC_ELEMS, w_lo + 2 * W_SRC_ELEMS,
                                                         attn, src, dst,
                                                         feat_src, feat_dst, alpha_out, deg);
    scan_phase1<<<SCAN_BLOCKS, 256, 0, stream>>>(deg, partial);
    scan_phase2<<<1, 128, 0, stream>>>(partial, boff, row_ptr);
    scan_phase3<<<SCAN_BLOCKS, 256, 0, stream>>>(deg, boff, row_ptr, cursor);
    bucket_fill_kernel<<<N_EDGES / 256, 256, 0, stream>>>(dst, src, alpha_out, cursor, esrc, exb);
    aggregate_kernel<<<(N_NODES + 3) / 4, 256, 0, stream>>>(row_ptr, esrc, exb,
                                                            feat_src, bias, seg_sum, rst_out);
    normalize_kernel<<<(N_EDGES * NH) / 256, 256, 0, stream>>>(seg_sum, dst, alpha_out);
}

// Round 2
// 687.024 us; speedup vs baseline: 1.2775x; 1.0789x over previous
//
#include <hip/hip_runtime.h>
#include <hip/hip_bf16.h>

#define N_NODES 100000
#define N_EDGES 1600000
#define IN_DIM 128
#define OUT_DIM 64
#define EDGE_DIM 32
#define NH 4
#define HD 16
#define NEG_SLOPE 0.2f

#define W_SRC_ELEMS (OUT_DIM * IN_DIM)   // 8192
#define W_EDGE_ELEMS (OUT_DIM * EDGE_DIM) // 2048
#define W_TOTAL (2 * W_SRC_ELEMS + W_EDGE_ELEMS) // 18432

typedef __attribute__((ext_vector_type(8))) short short8;
typedef __attribute__((ext_vector_type(4))) float floatx4;

// Split an fp32 octet into bf16 hi/lo fragments: x = hi + lo + O(eps^2 * x).
__device__ __forceinline__ void cvt_hilo(const float* __restrict__ p, short8& hi, short8& lo)
{
    float4 x0 = *(const float4*)p;
    float4 x1 = *(const float4*)(p + 4);
    float v[8] = {x0.x, x0.y, x0.z, x0.w, x1.x, x1.y, x1.z, x1.w};
#pragma unroll
    for (int j = 0; j < 8; ++j) {
        union { __hip_bfloat16 b; short s; } h, l;
        h.b = __float2bfloat16(v[j]);
        l.b = __float2bfloat16(v[j] - __bfloat162float(h.b));
        hi[j] = h.s;
        lo[j] = l.s;
    }
}

// ---------------------------------------------------------------------------
// Kernel W: precompute hi/lo bf16 split of W_src|W_dst|W_edge (one pass).
// ---------------------------------------------------------------------------
__global__ __launch_bounds__(256) void wsplit_kernel(
    const float* __restrict__ W_src,
    const float* __restrict__ W_dst,
    const float* __restrict__ W_edge,
    short* __restrict__ w_hi,
    short* __restrict__ w_lo)
{
    int g = blockIdx.x * 256 + threadIdx.x;
    if (g >= W_TOTAL) return;
    float v;
    if (g < W_SRC_ELEMS)            v = W_src[g];
    else if (g < 2 * W_SRC_ELEMS)   v = W_dst[g - W_SRC_ELEMS];
    else                            v = W_edge[g - 2 * W_SRC_ELEMS];
    union { __hip_bfloat16 b; short s; } h, l;
    h.b = __float2bfloat16(v);
    l.b = __float2bfloat16(v - __bfloat162float(h.b));
    w_hi[g] = h.s;
    w_lo[g] = l.s;
}

// ---------------------------------------------------------------------------
// Kernel A: feat_src = node_feat @ W_src^T, feat_dst = node_feat @ W_dst^T
// ---------------------------------------------------------------------------
__global__ __launch_bounds__(64) void node_proj_kernel(
    const float* __restrict__ node_feat,
    const short* __restrict__ w_hi,
    const short* __restrict__ w_lo,
    float* __restrict__ feat_src,
    float* __restrict__ feat_dst)
{
    const int lane = threadIdx.x;
    const int col  = lane & 15;
    const int quad = lane >> 4;
    const int m0   = blockIdx.x * 16;

    floatx4 acc[8];
#pragma unroll
    for (int t = 0; t < 8; ++t) acc[t] = (floatx4){0.f, 0.f, 0.f, 0.f};

#pragma unroll
    for (int kc = 0; kc < 4; ++kc) {
        short8 ahi, alo;
        cvt_hilo(node_feat + (size_t)(m0 + col) * IN_DIM + kc * 32 + quad * 8, ahi, alo);
#pragma unroll
        for (int t = 0; t < 8; ++t) {
            int o = (t < 4 ? 0 : OUT_DIM) + (t & 3) * 16 + col;
            size_t off = (size_t)o * IN_DIM + kc * 32 + quad * 8;
            short8 bhi = *(const short8*)(w_hi + off);
            short8 blo = *(const short8*)(w_lo + off);
            acc[t] = __builtin_amdgcn_mfma_f32_16x16x32_bf16(ahi, bhi, acc[t], 0, 0, 0);
            acc[t] = __builtin_amdgcn_mfma_f32_16x16x32_bf16(ahi, blo, acc[t], 0, 0, 0);
            acc[t] = __builtin_amdgcn_mfma_f32_16x16x32_bf16(alo, bhi, acc[t], 0, 0, 0);
        }
    }

#pragma unroll
    for (int t = 0; t < 8; ++t) {
        float* out = (t < 4) ? feat_src : feat_dst;
        int ob = (t & 3) * 16;
#pragma unroll
        for (int r = 0; r < 4; ++r) {
            int node = m0 + quad * 4 + r;
            out[(size_t)node * OUT_DIM + ob + col] = acc[t][r];
        }
    }
}

// ---------------------------------------------------------------------------
// Kernel B: edge logits + exp, 2 tiles (32 edges) per wave with interleaved
// phases: all index loads issued first, W-frags/attn hoisted (shared across
// tiles), then both tiles' gathers in flight together (2x outstanding VMEM).
// One atomic per edge (degree histogram).
// ---------------------------------------------------------------------------
__global__ __launch_bounds__(256) void edge_logits_kernel(
    const float* __restrict__ edge_feat,
    const short* __restrict__ we_hi,   // W_edge hi, [64][32]
    const short* __restrict__ we_lo,
    const float* __restrict__ attn,
    const int* __restrict__ src,
    const int* __restrict__ dst,
    const float* __restrict__ feat_src,
    const float* __restrict__ feat_dst,
    float* __restrict__ ex_out,
    int* __restrict__ deg)
{
    const int lane = threadIdx.x & 63;
    const int wave = threadIdx.x >> 6;
    const int col  = lane & 15;
    const int quad = lane >> 4;
    const size_t ebase0 = ((size_t)blockIdx.x * 4 + wave) * 32;   // 2 tiles x 16

    // phase 1: issue all src/dst loads (their latency hides under MFMA setup)
    int s[2][4], d[2][4];
#pragma unroll
    for (int u = 0; u < 2; ++u)
#pragma unroll
        for (int r = 0; r < 4; ++r) {
            s[u][r] = src[ebase0 + u * 16 + quad * 4 + r];
            d[u][r] = dst[ebase0 + u * 16 + quad * 4 + r];
        }

    // phase 2: edge_feat for both tiles
    short8 ahi[2], alo[2];
#pragma unroll
    for (int u = 0; u < 2; ++u)
        cvt_hilo(edge_feat + (ebase0 + u * 16 + col) * EDGE_DIM + quad * 8, ahi[u], alo[u]);

    float att[4];
#pragma unroll
    for (int t = 0; t < 4; ++t) att[t] = attn[t * 16 + col];

    // phase 3: MFMAs, W-frags loaded once and shared between the two tiles
    floatx4 acc[2][4];
#pragma unroll
    for (int t = 0; t < 4; ++t) {
        size_t off = (size_t)(t * 16 + col) * EDGE_DIM + quad * 8;
        short8 bhi = *(const short8*)(we_hi + off);
        short8 blo = *(const short8*)(we_lo + off);
#pragma unroll
        for (int u = 0; u < 2; ++u) {
            floatx4 c = (floatx4){0.f, 0.f, 0.f, 0.f};
            c = __builtin_amdgcn_mfma_f32_16x16x32_bf16(ahi[u], bhi, c, 0, 0, 0);
            c = __builtin_amdgcn_mfma_f32_16x16x32_bf16(ahi[u], blo, c, 0, 0, 0);
            c = __builtin_amdgcn_mfma_f32_16x16x32_bf16(alo[u], bhi, c, 0, 0, 0);
            acc[u][t] = c;
        }
    }

    // phase 4: fs/fd gathers (2 tiles interleaved), leaky-relu, attn dot
    float sums[2][16];
#pragma unroll
    for (int u = 0; u < 2; ++u)
#pragma unroll
        for (int r = 0; r < 4; ++r)
#pragma unroll
            for (int t = 0; t < 4; ++t) {
                float v = acc[u][t][r]
                        + feat_src[(size_t)s[u][r] * OUT_DIM + t * 16 + col]
                        + feat_dst[(size_t)d[u][r] * OUT_DIM + t * 16 + col];
                v = (v > 0.f) ? v : NEG_SLOPE * v;
                float p = v * att[t];
                p += __shfl_xor(p, 1);
                p += __shfl_xor(p, 2);
                p += __shfl_xor(p, 4);
                p += __shfl_xor(p, 8);
                sums[u][r * 4 + t] = p;
            }

    // phase 5: per-tile epilogue
    const int j = col;
    const int rsel = j >> 2;
#pragma unroll
    for (int u = 0; u < 2; ++u) {
        float logit = sums[u][0];
#pragma unroll
        for (int i = 1; i < 16; ++i) logit = (j == i) ? sums[u][i] : logit;
        float ev = __expf(logit);
        ex_out[(ebase0 + u * 16) * NH + lane] = ev;

        int dd = d[u][0];
#pragma unroll
        for (int r = 1; r < 4; ++r) dd = (rsel == r) ? d[u][r] : dd;
        if ((j & 3) == 0) atomicAdd(&deg[dd], 1);
    }
}

// ---------------------------------------------------------------------------
// Hierarchical scan of deg[N] -> row_ptr[N+1] (exclusive), cursor[N].
// ---------------------------------------------------------------------------
#define SCAN_BLOCKS 98

__global__ __launch_bounds__(256) void scan_phase1(
    const int* __restrict__ deg, int* __restrict__ partial)
{
    __shared__ int red[256];
    const int tid = threadIdx.x;
    const int base = blockIdx.x * 1024 + tid * 4;
    int s = 0;
#pragma unroll
    for (int i = 0; i < 4; ++i) {
        int idx = base + i;
        if (idx < N_NODES) s += deg[idx];
    }
    red[tid] = s;
    __syncthreads();
    for (int off = 128; off > 0; off >>= 1) {
        if (tid < off) red[tid] += red[tid + off];
        __syncthreads();
    }
    if (tid == 0) partial[blockIdx.x] = red[0];
}

__global__ __launch_bounds__(128) void scan_phase2(
    const int* __restrict__ partial, int* __restrict__ block_off, int* __restrict__ row_ptr)
{
    __shared__ int buf[128];
    const int tid = threadIdx.x;
    buf[tid] = (tid < SCAN_BLOCKS) ? partial[tid] : 0;
    __syncthreads();
    for (int off = 1; off < 128; off <<= 1) {
        int v = buf[tid];
        int add = (tid >= off) ? buf[tid - off] : 0;
        __syncthreads();
        buf[tid] = v + add;
        __syncthreads();
    }
    if (tid < SCAN_BLOCKS) block_off[tid] = (tid > 0) ? buf[tid - 1] : 0;
    if (tid == 0) row_ptr[N_NODES] = N_EDGES;
}

__global__ __launch_bounds__(256) void scan_phase3(
    const int* __restrict__ deg, const int* __restrict__ block_off,
    int* __restrict__ row_ptr, int* __restrict__ cursor)
{
    __shared__ int tsum[256];
    const int tid = threadIdx.x;
    const int base = blockIdx.x * 1024 + tid * 4;
    int d[4];
    int s = 0;
#pragma unroll
    for (int i = 0; i < 4; ++i) {
        int idx = base + i;
        d[i] = (idx < N_NODES) ? deg[idx] : 0;
        s += d[i];
    }
    tsum[tid] = s;
    __syncthreads();
    for (int off = 1; off < 256; off <<= 1) {
        int v = tsum[tid];
        int add = (tid >= off) ? tsum[tid - off] : 0;
        __syncthreads();
        tsum[tid] = v + add;
        __syncthreads();
    }
    int prefix = block_off[blockIdx.x] + ((tid > 0) ? tsum[tid - 1] : 0);
#pragma unroll
    for (int i = 0; i < 4; ++i) {
        int idx = base + i;
        if (idx < N_NODES) {
            row_ptr[idx] = prefix;
            cursor[idx]  = prefix;
            prefix += d[i];
        }
    }
}

// ---------------------------------------------------------------------------
// Kernel F: bucket-fill in CONSUMPTION ORDER.
//   esrc[pos] = src[e]; exb[pos] = ex[e] (float4)
// ---------------------------------------------------------------------------
__global__ __launch_bounds__(256) void bucket_fill_kernel(
    const int* __restrict__ dst,
    const int* __restrict__ src,
    const float* __restrict__ ex,      // [E][4], original edge order
    int* __restrict__ cursor,
    int* __restrict__ esrc,            // [E]
    float* __restrict__ exb)           // [E][4], bucket order
{
    int e = blockIdx.x * 256 + threadIdx.x;
    int pos = atomicAdd(&cursor[dst[e]], 1);
    esrc[pos] = src[e];
    float4 v = ((const float4*)ex)[e];
    ((float4*)exb)[pos] = v;
}

// ---------------------------------------------------------------------------
// Kernel G: gather-side aggregation, 4-wide pipelined inner loop.
// 4 independent feat_src gathers in flight per iteration (vs 1 before).
// ---------------------------------------------------------------------------
__global__ __launch_bounds__(256) void aggregate_kernel(
    const int* __restrict__ row_ptr,
    const int* __restrict__ esrc,
    const float* __restrict__ exb,
    const float* __restrict__ feat_src,
    const float* __restrict__ bias,
    float* __restrict__ seg_sum,
    float* __restrict__ out)
{
    const int node = blockIdx.x * 4 + (threadIdx.x >> 6);
    if (node >= N_NODES) return;
    const int lane = threadIdx.x & 63;
    const int h = lane >> 4;

    const int start = row_ptr[node];
    const int end   = row_ptr[node + 1];

    float acc = 0.f;
    float ssum = 0.f;

    int j = start;
    for (; j + 4 <= end; j += 4) {
        int s0 = esrc[j + 0];
        int s1 = esrc[j + 1];
        int s2 = esrc[j + 2];
        int s3 = esrc[j + 3];
        float e0 = exb[(size_t)(j + 0) * NH + h];
        float e1 = exb[(size_t)(j + 1) * NH + h];
        float e2 = exb[(size_t)(j + 2) * NH + h];
        float e3 = exb[(size_t)(j + 3) * NH + h];
        float f0 = feat_src[(size_t)s0 * OUT_DIM + lane];
        float f1 = feat_src[(size_t)s1 * OUT_DIM + lane];
        float f2 = feat_src[(size_t)s2 * OUT_DIM + lane];
        float f3 = feat_src[(size_t)s3 * OUT_DIM + lane];
        acc = fmaf(f0, e0, acc);
        acc = fmaf(f1, e1, acc);
        acc = fmaf(f2, e2, acc);
        acc = fmaf(f3, e3, acc);
        ssum += e0 + e1 + e2 + e3;
    }
    for (; j < end; ++j) {
        int s = esrc[j];
        float ev = exb[(size_t)j * NH + h];
        acc = fmaf(feat_src[(size_t)s * OUT_DIM + lane], ev, acc);
        ssum += ev;
    }

    if ((lane & 15) == 0) seg_sum[(size_t)node * NH + h] = ssum;
    float inv = (ssum > 0.f) ? 1.f / ssum : 0.f;
    out[(size_t)node * OUT_DIM + lane] = fmaf(acc, inv, bias[lane]);
}

// ---------------------------------------------------------------------------
// Kernel C: alpha = ex / seg_sum[dst]  (one thread per edge, float4)
// ---------------------------------------------------------------------------
__global__ __launch_bounds__(256) void normalize_kernel(
    const float* __restrict__ seg_sum,
    const int* __restrict__ dst,
    float* __restrict__ alpha)
{
    int e = blockIdx.x * 256 + threadIdx.x;   // e < E
    int d = dst[e];
    float4 ex4 = ((const float4*)alpha)[e];
    float4 ss  = ((const float4*)seg_sum)[d];
    float4 r;
    r.x = ex4.x / ss.x;
    r.y = ex4.y / ss.y;
    r.z = ex4.z / ss.z;
    r.w = ex4.w / ss.w;
    ((float4*)alpha)[e] = r;
}

// ---------------------------------------------------------------------------
extern "C" void kernel_launch(void* const* d_in, const int* in_sizes, int n_in,
                              void* d_out, int out_size, void* d_ws, size_t ws_size,
                              hipStream_t stream)
{
    const float* node_feat = (const float*)d_in[0];
    const float* edge_feat = (const float*)d_in[1];
    const float* W_src     = (const float*)d_in[2];
    const float* W_dst     = (const float*)d_in[3];
    const float* W_edge    = (const float*)d_in[4];
    const float* attn      = (const float*)d_in[5];
    const float* bias      = (const float*)d_in[6];
    const int* src = (const int*)d_in[7];
    const int* dst = (const int*)d_in[8];

    // workspace layout (exb aliases feat_dst, dead after edge_logits)
    float* ws       = (float*)d_ws;
    float* feat_src = ws;                                        // N*64 floats
    float* feat_dst = feat_src + (size_t)N_NODES * OUT_DIM;      // N*64 floats (== E*NH!)
    float* exb      = feat_dst;                                  // reuse after edge_logits
    float* seg_sum  = feat_dst + (size_t)N_NODES * OUT_DIM;      // N*4 floats
    int*   deg      = (int*)(seg_sum + (size_t)N_NODES * NH);    // N ints
    int*   row_ptr  = deg + N_NODES;                             // N+1
    int*   cursor   = row_ptr + N_NODES + 1;                     // N
    int*   esrc     = cursor + N_NODES;                          // E ints
    int*   partial  = esrc + N_EDGES;                            // 98
    int*   boff     = partial + 128;                             // 98
    short* w_hi     = (short*)(boff + 128);                      // 18432 shorts
    short* w_lo     = w_hi + W_TOTAL;

    float* rst_out   = (float*)d_out;
    float* alpha_out = rst_out + (size_t)N_NODES * OUT_DIM;   // holds ex, then alpha

    hipMemsetAsync(deg, 0, (size_t)N_NODES * sizeof(int), stream);

    wsplit_kernel<<<(W_TOTAL + 255) / 256, 256, 0, stream>>>(W_src, W_dst, W_edge, w_hi, w_lo);
    node_proj_kernel<<<N_NODES / 16, 64, 0, stream>>>(node_feat, w_hi, w_lo, feat_src, feat_dst);
    edge_logits_kernel<<<N_EDGES / 128, 256, 0, stream>>>(edge_feat,
                                                          w_hi + 2 * W_SRC_ELEMS, w_lo + 2 * W_SRC_ELEMS,
                                                          attn, src, dst,
                                                          feat_src, feat_dst, alpha_out, deg);
    scan_phase1<<<SCAN_BLOCKS, 256, 0, stream>>>(deg, partial);
    scan_phase2<<<1, 128, 0, stream>>>(partial, boff, row_ptr);
    scan_phase3<<<SCAN_BLOCKS, 256, 0, stream>>>(deg, boff, row_ptr, cursor);
    bucket_fill_kernel<<<N_EDGES / 256, 256, 0, stream>>>(dst, src, alpha_out, cursor, esrc, exb);
    aggregate_kernel<<<(N_NODES + 3) / 4, 256, 0, stream>>>(row_ptr, esrc, exb,
                                                            feat_src, bias, seg_sum, rst_out);
    normalize_kernel<<<N_EDGES / 256, 256, 0, stream>>>(seg_sum, dst, alpha_out);
}

// Round 3
// 675.010 us; speedup vs baseline: 1.3003x; 1.0178x over previous
//
#include <hip/hip_runtime.h>
#include <hip/hip_bf16.h>

#define N_NODES 100000
#define N_EDGES 1600000
#define IN_DIM 128
#define OUT_DIM 64
#define EDGE_DIM 32
#define NH 4
#define HD 16
#define NEG_SLOPE 0.2f

#define W_SRC_ELEMS (OUT_DIM * IN_DIM)   // 8192
#define W_EDGE_ELEMS (OUT_DIM * EDGE_DIM) // 2048
#define W_TOTAL (2 * W_SRC_ELEMS + W_EDGE_ELEMS) // 18432

typedef __attribute__((ext_vector_type(8))) short short8;
typedef __attribute__((ext_vector_type(4))) float floatx4;

// Split an fp32 octet into bf16 hi/lo fragments: x = hi + lo + O(eps^2 * x).
__device__ __forceinline__ void cvt_hilo(const float* __restrict__ p, short8& hi, short8& lo)
{
    float4 x0 = *(const float4*)p;
    float4 x1 = *(const float4*)(p + 4);
    float v[8] = {x0.x, x0.y, x0.z, x0.w, x1.x, x1.y, x1.z, x1.w};
#pragma unroll
    for (int j = 0; j < 8; ++j) {
        union { __hip_bfloat16 b; short s; } h, l;
        h.b = __float2bfloat16(v[j]);
        l.b = __float2bfloat16(v[j] - __bfloat162float(h.b));
        hi[j] = h.s;
        lo[j] = l.s;
    }
}

// ---------------------------------------------------------------------------
// Kernel W: precompute hi/lo bf16 split of W_src|W_dst|W_edge (one pass).
// ---------------------------------------------------------------------------
__global__ __launch_bounds__(256) void wsplit_kernel(
    const float* __restrict__ W_src,
    const float* __restrict__ W_dst,
    const float* __restrict__ W_edge,
    short* __restrict__ w_hi,
    short* __restrict__ w_lo)
{
    int g = blockIdx.x * 256 + threadIdx.x;
    if (g >= W_TOTAL) return;
    float v;
    if (g < W_SRC_ELEMS)            v = W_src[g];
    else if (g < 2 * W_SRC_ELEMS)   v = W_dst[g - W_SRC_ELEMS];
    else                            v = W_edge[g - 2 * W_SRC_ELEMS];
    union { __hip_bfloat16 b; short s; } h, l;
    h.b = __float2bfloat16(v);
    l.b = __float2bfloat16(v - __bfloat162float(h.b));
    w_hi[g] = h.s;
    w_lo[g] = l.s;
}

// ---------------------------------------------------------------------------
// Kernel A: feat_src = node_feat @ W_src^T, feat_dst = node_feat @ W_dst^T
// ---------------------------------------------------------------------------
__global__ __launch_bounds__(64) void node_proj_kernel(
    const float* __restrict__ node_feat,
    const short* __restrict__ w_hi,
    const short* __restrict__ w_lo,
    float* __restrict__ feat_src,
    float* __restrict__ feat_dst)
{
    const int lane = threadIdx.x;
    const int col  = lane & 15;
    const int quad = lane >> 4;
    const int m0   = blockIdx.x * 16;

    floatx4 acc[8];
#pragma unroll
    for (int t = 0; t < 8; ++t) acc[t] = (floatx4){0.f, 0.f, 0.f, 0.f};

#pragma unroll
    for (int kc = 0; kc < 4; ++kc) {
        short8 ahi, alo;
        cvt_hilo(node_feat + (size_t)(m0 + col) * IN_DIM + kc * 32 + quad * 8, ahi, alo);
#pragma unroll
        for (int t = 0; t < 8; ++t) {
            int o = (t < 4 ? 0 : OUT_DIM) + (t & 3) * 16 + col;
            size_t off = (size_t)o * IN_DIM + kc * 32 + quad * 8;
            short8 bhi = *(const short8*)(w_hi + off);
            short8 blo = *(const short8*)(w_lo + off);
            acc[t] = __builtin_amdgcn_mfma_f32_16x16x32_bf16(ahi, bhi, acc[t], 0, 0, 0);
            acc[t] = __builtin_amdgcn_mfma_f32_16x16x32_bf16(ahi, blo, acc[t], 0, 0, 0);
            acc[t] = __builtin_amdgcn_mfma_f32_16x16x32_bf16(alo, bhi, acc[t], 0, 0, 0);
        }
    }

#pragma unroll
    for (int t = 0; t < 8; ++t) {
        float* out = (t < 4) ? feat_src : feat_dst;
        int ob = (t & 3) * 16;
#pragma unroll
        for (int r = 0; r < 4; ++r) {
            int node = m0 + quad * 4 + r;
            out[(size_t)node * OUT_DIM + ob + col] = acc[t][r];
        }
    }
}

// ---------------------------------------------------------------------------
// Kernel B: edge logits + exp, 2 tiles (32 edges) per wave.
// Reduction over the 16 lanes x 16 combos is a 4-step butterfly tree
// (15 shfls/tile instead of 64 + select chain): at each step lanes keep the
// half of the combo set matching their own lane bit, so combo j's sum lands
// directly in lane j (j>>2 = r, j&3 = h).
// ---------------------------------------------------------------------------
__global__ __launch_bounds__(256) void edge_logits_kernel(
    const float* __restrict__ edge_feat,
    const short* __restrict__ we_hi,   // W_edge hi, [64][32]
    const short* __restrict__ we_lo,
    const float* __restrict__ attn,
    const int* __restrict__ src,
    const int* __restrict__ dst,
    const float* __restrict__ feat_src,
    const float* __restrict__ feat_dst,
    float* __restrict__ ex_out,
    int* __restrict__ deg)
{
    const int lane = threadIdx.x & 63;
    const int wave = threadIdx.x >> 6;
    const int col  = lane & 15;
    const int quad = lane >> 4;
    const size_t ebase0 = ((size_t)blockIdx.x * 4 + wave) * 32;   // 2 tiles x 16

    // phase 1: issue all src/dst loads
    int s[2][4], d[2][4];
#pragma unroll
    for (int u = 0; u < 2; ++u)
#pragma unroll
        for (int r = 0; r < 4; ++r) {
            s[u][r] = src[ebase0 + u * 16 + quad * 4 + r];
            d[u][r] = dst[ebase0 + u * 16 + quad * 4 + r];
        }

    // phase 2: edge_feat for both tiles
    short8 ahi[2], alo[2];
#pragma unroll
    for (int u = 0; u < 2; ++u)
        cvt_hilo(edge_feat + (ebase0 + u * 16 + col) * EDGE_DIM + quad * 8, ahi[u], alo[u]);

    float att[4];
#pragma unroll
    for (int t = 0; t < 4; ++t) att[t] = attn[t * 16 + col];

    // phase 3: MFMAs, W-frags loaded once and shared between the two tiles
    floatx4 acc[2][4];
#pragma unroll
    for (int t = 0; t < 4; ++t) {
        size_t off = (size_t)(t * 16 + col) * EDGE_DIM + quad * 8;
        short8 bhi = *(const short8*)(we_hi + off);
        short8 blo = *(const short8*)(we_lo + off);
#pragma unroll
        for (int u = 0; u < 2; ++u) {
            floatx4 c = (floatx4){0.f, 0.f, 0.f, 0.f};
            c = __builtin_amdgcn_mfma_f32_16x16x32_bf16(ahi[u], bhi, c, 0, 0, 0);
            c = __builtin_amdgcn_mfma_f32_16x16x32_bf16(ahi[u], blo, c, 0, 0, 0);
            c = __builtin_amdgcn_mfma_f32_16x16x32_bf16(alo[u], bhi, c, 0, 0, 0);
            acc[u][t] = c;
        }
    }

    const int j = col;
    const int rsel = j >> 2;

#pragma unroll
    for (int u = 0; u < 2; ++u) {
        // per-lane partial contributions p[r*4+t]; no reduce yet
        float p[16];
#pragma unroll
        for (int r = 0; r < 4; ++r)
#pragma unroll
            for (int t = 0; t < 4; ++t) {
                float v = acc[u][t][r]
                        + feat_src[(size_t)s[u][r] * OUT_DIM + t * 16 + col]
                        + feat_dst[(size_t)d[u][r] * OUT_DIM + t * 16 + col];
                v = (v > 0.f) ? v : NEG_SLOPE * v;
                p[r * 4 + t] = v * att[t];
            }

        // butterfly tree: after step m, lane keeps combos whose bit == lane bit
        {
            const bool u8 = (col & 8) != 0;
#pragma unroll
            for (int i = 0; i < 8; ++i) {
                float keep = u8 ? p[i + 8] : p[i];
                float send = u8 ? p[i] : p[i + 8];
                p[i] = keep + __shfl_xor(send, 8);
            }
            const bool u4 = (col & 4) != 0;
#pragma unroll
            for (int i = 0; i < 4; ++i) {
                float keep = u4 ? p[i + 4] : p[i];
                float send = u4 ? p[i] : p[i + 4];
                p[i] = keep + __shfl_xor(send, 4);
            }
            const bool u2 = (col & 2) != 0;
#pragma unroll
            for (int i = 0; i < 2; ++i) {
                float keep = u2 ? p[i + 2] : p[i];
                float send = u2 ? p[i] : p[i + 2];
                p[i] = keep + __shfl_xor(send, 2);
            }
            const bool u1 = (col & 1) != 0;
            {
                float keep = u1 ? p[1] : p[0];
                float send = u1 ? p[0] : p[1];
                p[0] = keep + __shfl_xor(send, 1);
            }
        }

        float ev = __expf(p[0]);
        ex_out[(ebase0 + u * 16) * NH + lane] = ev;

        int dd = d[u][0];
#pragma unroll
        for (int r = 1; r < 4; ++r) dd = (rsel == r) ? d[u][r] : dd;
        if ((j & 3) == 0) atomicAdd(&deg[dd], 1);
    }
}

// ---------------------------------------------------------------------------
// Hierarchical scan of deg[N] -> row_ptr[N+1] (exclusive), cursor[N].
// ---------------------------------------------------------------------------
#define SCAN_BLOCKS 98

__global__ __launch_bounds__(256) void scan_phase1(
    const int* __restrict__ deg, int* __restrict__ partial)
{
    __shared__ int red[256];
    const int tid = threadIdx.x;
    const int base = blockIdx.x * 1024 + tid * 4;
    int s = 0;
#pragma unroll
    for (int i = 0; i < 4; ++i) {
        int idx = base + i;
        if (idx < N_NODES) s += deg[idx];
    }
    red[tid] = s;
    __syncthreads();
    for (int off = 128; off > 0; off >>= 1) {
        if (tid < off) red[tid] += red[tid + off];
        __syncthreads();
    }
    if (tid == 0) partial[blockIdx.x] = red[0];
}

__global__ __launch_bounds__(128) void scan_phase2(
    const int* __restrict__ partial, int* __restrict__ block_off, int* __restrict__ row_ptr)
{
    __shared__ int buf[128];
    const int tid = threadIdx.x;
    buf[tid] = (tid < SCAN_BLOCKS) ? partial[tid] : 0;
    __syncthreads();
    for (int off = 1; off < 128; off <<= 1) {
        int v = buf[tid];
        int add = (tid >= off) ? buf[tid - off] : 0;
        __syncthreads();
        buf[tid] = v + add;
        __syncthreads();
    }
    if (tid < SCAN_BLOCKS) block_off[tid] = (tid > 0) ? buf[tid - 1] : 0;
    if (tid == 0) row_ptr[N_NODES] = N_EDGES;
}

__global__ __launch_bounds__(256) void scan_phase3(
    const int* __restrict__ deg, const int* __restrict__ block_off,
    int* __restrict__ row_ptr, int* __restrict__ cursor)
{
    __shared__ int tsum[256];
    const int tid = threadIdx.x;
    const int base = blockIdx.x * 1024 + tid * 4;
    int d[4];
    int s = 0;
#pragma unroll
    for (int i = 0; i < 4; ++i) {
        int idx = base + i;
        d[i] = (idx < N_NODES) ? deg[idx] : 0;
        s += d[i];
    }
    tsum[tid] = s;
    __syncthreads();
    for (int off = 1; off < 256; off <<= 1) {
        int v = tsum[tid];
        int add = (tid >= off) ? tsum[tid - off] : 0;
        __syncthreads();
        tsum[tid] = v + add;
        __syncthreads();
    }
    int prefix = block_off[blockIdx.x] + ((tid > 0) ? tsum[tid - 1] : 0);
#pragma unroll
    for (int i = 0; i < 4; ++i) {
        int idx = base + i;
        if (idx < N_NODES) {
            row_ptr[idx] = prefix;
            cursor[idx]  = prefix;
            prefix += d[i];
        }
    }
}

// ---------------------------------------------------------------------------
// Kernel F: bucket-fill in CONSUMPTION ORDER.
//   esrc[pos] = src[e]; exb[pos] = ex[e] (float4)
// ---------------------------------------------------------------------------
__global__ __launch_bounds__(256) void bucket_fill_kernel(
    const int* __restrict__ dst,
    const int* __restrict__ src,
    const float* __restrict__ ex,      // [E][4], original edge order
    int* __restrict__ cursor,
    int* __restrict__ esrc,            // [E]
    float* __restrict__ exb)           // [E][4], bucket order
{
    int e = blockIdx.x * 256 + threadIdx.x;
    int pos = atomicAdd(&cursor[dst[e]], 1);
    esrc[pos] = src[e];
    float4 v = ((const float4*)ex)[e];
    ((float4*)exb)[pos] = v;
}

// ---------------------------------------------------------------------------
// Kernel G: gather-side aggregation, 8-wide pipelined inner loop.
// 8 independent feat_src gathers in flight per iteration.
// ---------------------------------------------------------------------------
__global__ __launch_bounds__(256) void aggregate_kernel(
    const int* __restrict__ row_ptr,
    const int* __restrict__ esrc,
    const float* __restrict__ exb,
    const float* __restrict__ feat_src,
    const float* __restrict__ bias,
    float* __restrict__ seg_sum,
    float* __restrict__ out)
{
    const int node = blockIdx.x * 4 + (threadIdx.x >> 6);
    if (node >= N_NODES) return;
    const int lane = threadIdx.x & 63;
    const int h = lane >> 4;

    const int start = row_ptr[node];
    const int end   = row_ptr[node + 1];

    float acc = 0.f;
    float ssum = 0.f;

    int j = start;
    for (; j + 8 <= end; j += 8) {
        int   s_[8];
        float e_[8];
        float f_[8];
#pragma unroll
        for (int i = 0; i < 8; ++i) s_[i] = esrc[j + i];
#pragma unroll
        for (int i = 0; i < 8; ++i) e_[i] = exb[(size_t)(j + i) * NH + h];
#pragma unroll
        for (int i = 0; i < 8; ++i) f_[i] = feat_src[(size_t)s_[i] * OUT_DIM + lane];
#pragma unroll
        for (int i = 0; i < 8; ++i) {
            acc = fmaf(f_[i], e_[i], acc);
            ssum += e_[i];
        }
    }
    for (; j + 4 <= end; j += 4) {
        int   s_[4];
        float e_[4];
        float f_[4];
#pragma unroll
        for (int i = 0; i < 4; ++i) s_[i] = esrc[j + i];
#pragma unroll
        for (int i = 0; i < 4; ++i) e_[i] = exb[(size_t)(j + i) * NH + h];
#pragma unroll
        for (int i = 0; i < 4; ++i) f_[i] = feat_src[(size_t)s_[i] * OUT_DIM + lane];
#pragma unroll
        for (int i = 0; i < 4; ++i) {
            acc = fmaf(f_[i], e_[i], acc);
            ssum += e_[i];
        }
    }
    for (; j < end; ++j) {
        int s = esrc[j];
        float ev = exb[(size_t)j * NH + h];
        acc = fmaf(feat_src[(size_t)s * OUT_DIM + lane], ev, acc);
        ssum += ev;
    }

    if ((lane & 15) == 0) seg_sum[(size_t)node * NH + h] = ssum;
    float inv = (ssum > 0.f) ? 1.f / ssum : 0.f;
    out[(size_t)node * OUT_DIM + lane] = fmaf(acc, inv, bias[lane]);
}

// ---------------------------------------------------------------------------
// Kernel C: alpha = ex / seg_sum[dst]  (one thread per edge, float4)
// ---------------------------------------------------------------------------
__global__ __launch_bounds__(256) void normalize_kernel(
    const float* __restrict__ seg_sum,
    const int* __restrict__ dst,
    float* __restrict__ alpha)
{
    int e = blockIdx.x * 256 + threadIdx.x;   // e < E
    int d = dst[e];
    float4 ex4 = ((const float4*)alpha)[e];
    float4 ss  = ((const float4*)seg_sum)[d];
    float4 r;
    r.x = ex4.x / ss.x;
    r.y = ex4.y / ss.y;
    r.z = ex4.z / ss.z;
    r.w = ex4.w / ss.w;
    ((float4*)alpha)[e] = r;
}

// ---------------------------------------------------------------------------
extern "C" void kernel_launch(void* const* d_in, const int* in_sizes, int n_in,
                              void* d_out, int out_size, void* d_ws, size_t ws_size,
                              hipStream_t stream)
{
    const float* node_feat = (const float*)d_in[0];
    const float* edge_feat = (const float*)d_in[1];
    const float* W_src     = (const float*)d_in[2];
    const float* W_dst     = (const float*)d_in[3];
    const float* W_edge    = (const float*)d_in[4];
    const float* attn      = (const float*)d_in[5];
    const float* bias      = (const float*)d_in[6];
    const int* src = (const int*)d_in[7];
    const int* dst = (const int*)d_in[8];

    // workspace layout (exb aliases feat_dst, dead after edge_logits)
    float* ws       = (float*)d_ws;
    float* feat_src = ws;                                        // N*64 floats
    float* feat_dst = feat_src + (size_t)N_NODES * OUT_DIM;      // N*64 floats (== E*NH!)
    float* exb      = feat_dst;                                  // reuse after edge_logits
    float* seg_sum  = feat_dst + (size_t)N_NODES * OUT_DIM;      // N*4 floats
    int*   deg      = (int*)(seg_sum + (size_t)N_NODES * NH);    // N ints
    int*   row_ptr  = deg + N_NODES;                             // N+1
    int*   cursor   = row_ptr + N_NODES + 1;                     // N
    int*   esrc     = cursor + N_NODES;                          // E ints
    int*   partial  = esrc + N_EDGES;                            // 98
    int*   boff     = partial + 128;                             // 98
    short* w_hi     = (short*)(boff + 128);                      // 18432 shorts
    short* w_lo     = w_hi + W_TOTAL;

    float* rst_out   = (float*)d_out;
    float* alpha_out = rst_out + (size_t)N_NODES * OUT_DIM;   // holds ex, then alpha

    hipMemsetAsync(deg, 0, (size_t)N_NODES * sizeof(int), stream);

    wsplit_kernel<<<(W_TOTAL + 255) / 256, 256, 0, stream>>>(W_src, W_dst, W_edge, w_hi, w_lo);
    node_proj_kernel<<<N_NODES / 16, 64, 0, stream>>>(node_feat, w_hi, w_lo, feat_src, feat_dst);
    edge_logits_kernel<<<N_EDGES / 128, 256, 0, stream>>>(edge_feat,
                                                          w_hi + 2 * W_SRC_ELEMS, w_lo + 2 * W_SRC_ELEMS,
                                                          attn, src, dst,
                                                          feat_src, feat_dst, alpha_out, deg);
    scan_phase1<<<SCAN_BLOCKS, 256, 0, stream>>>(deg, partial);
    scan_phase2<<<1, 128, 0, stream>>>(partial, boff, row_ptr);
    scan_phase3<<<SCAN_BLOCKS, 256, 0, stream>>>(deg, boff, row_ptr, cursor);
    bucket_fill_kernel<<<N_EDGES / 256, 256, 0, stream>>>(dst, src, alpha_out, cursor, esrc, exb);
    aggregate_kernel<<<(N_NODES + 3) / 4, 256, 0, stream>>>(row_ptr, esrc, exb,
                                                            feat_src, bias, seg_sum, rst_out);
    normalize_kernel<<<N_EDGES / 256, 256, 0, stream>>>(seg_sum, dst, alpha_out);
}